// Round 1
// baseline (208.497 us; speedup 1.0000x reference)
//
#include <hip/hip_runtime.h>

#define T_N 500000
#define U_N 1000000
#define G_N 250000

// Select r[j] for dynamic j in [0,7] from a register array via cndmask chain
// (keeps the ceff fixed-point iteration free of dependent memory loads).
__device__ __forceinline__ float sel8(const float (&r)[8], int j) {
    float v = r[0];
#pragma unroll
    for (int k = 1; k < 8; ++k) v = (j >= k) ? r[k] : v;
    return v;
}

__global__ void init_gsum_kernel(float* __restrict__ gsum) {
    int i = blockIdx.x * blockDim.x + threadIdx.x;
    if (i < G_N) gsum[i] = 0.0f;
}

__global__ void exp_sum_kernel(const float* __restrict__ U,
                               const int* __restrict__ gid,
                               float* __restrict__ wout,
                               float* __restrict__ gsum) {
    int i = blockIdx.x * blockDim.x + threadIdx.x;
    if (i < U_N) {
        float w = expf(U[i]);
        wout[i] = w;
        atomicAdd(&gsum[gid[i]], w);
    }
}

__global__ void norm_w_kernel(const int* __restrict__ gid,
                              float* __restrict__ wout,
                              const float* __restrict__ gsum) {
    int i = blockIdx.x * blockDim.x + threadIdx.x;
    if (i < U_N) wout[i] = wout[i] / gsum[gid[i]];
}

__global__ void __launch_bounds__(256)
timing_kernel(const float2* __restrict__ in_arr,
              const float2* __restrict__ in_slew,
              const float* __restrict__ c1,
              const float* __restrict__ c2,
              const int* __restrict__ arc_r,
              const int* __restrict__ arc_f,
              const int* __restrict__ una,
              const float* __restrict__ dtab,   // [A,8,8]
              const float* __restrict__ stab,   // [A,8,8]
              const float* __restrict__ sidx,   // [A,8] slew axis
              const float* __restrict__ lidx,   // [A,8] load axis
              float4* __restrict__ out)         // [T] = (arr_r, arr_f, slew_r, slew_f)
{
    int t = blockIdx.x * blockDim.x + threadIdx.x;
    if (t >= T_N) return;

    float2 ia = in_arr[t];
    float2 is = in_slew[t];
    float c1f = c1[t] / 1.0e15f;
    float c2f = c2[t] / 1.0e15f;
    int arcs0 = arc_r[t];
    int arcs1 = arc_f[t];

    float res_arr[2], res_slew[2];

#pragma unroll
    for (int col = 0; col < 2; ++col) {
        int arc = (col == 0) ? arcs0 : arcs1;
        int u   = una[arc];
        int rf  = u ^ col;                      // which rise/fall input to use
        float slew = rf ? is.y : is.x;
        float arr  = rf ? ia.y : ia.x;

        // ---- slew axis interval (fixed for this item) ----
        float s[8];
        {
            const float4* p = (const float4*)(sidx + (size_t)arc * 8);
            float4 q0 = p[0], q1 = p[1];
            s[0]=q0.x; s[1]=q0.y; s[2]=q0.z; s[3]=q0.w;
            s[4]=q1.x; s[5]=q1.y; s[6]=q1.z; s[7]=q1.w;
        }
        int cnt = 0;
#pragma unroll
        for (int k = 0; k < 8; ++k) cnt += (s[k] <= slew) ? 1 : 0;
        int i0 = min(max(cnt - 1, 0), 6);
        float x0 = sel8(s, i0);
        float x1 = sel8(s, i0 + 1);
        float a = (slew - x0) / (x1 - x0);

        // ---- load axis values ----
        float cx[8];
        {
            const float4* p = (const float4*)(lidx + (size_t)arc * 8);
            float4 q0 = p[0], q1 = p[1];
            cx[0]=q0.x; cx[1]=q0.y; cx[2]=q0.z; cx[3]=q0.w;
            cx[4]=q1.x; cx[5]=q1.y; cx[6]=q1.z; cx[7]=q1.w;
        }

        // ---- delay table rows i0, i1 (contiguous 16 floats) ----
        float d0[8], d1[8];
        {
            const float4* p = (const float4*)(dtab + (size_t)arc * 64 + (size_t)i0 * 8);
            float4 q0 = p[0], q1 = p[1], q2 = p[2], q3 = p[3];
            d0[0]=q0.x; d0[1]=q0.y; d0[2]=q0.z; d0[3]=q0.w;
            d0[4]=q1.x; d0[5]=q1.y; d0[6]=q1.z; d0[7]=q1.w;
            d1[0]=q2.x; d1[1]=q2.y; d1[2]=q2.z; d1[3]=q2.w;
            d1[4]=q3.x; d1[5]=q3.y; d1[6]=q3.z; d1[7]=q3.w;
        }

        float om_a = 1.0f - a;
        float slew_den = fmaxf(slew, 1e-30f);

        // ---- ceff fixed point: 3 iterations ----
        float ceff = fmaxf(c1f + c2f, 1e-30f);
#pragma unroll
        for (int it = 0; it < 3; ++it) {
            int jc = 0;
#pragma unroll
            for (int k = 0; k < 8; ++k) jc += (cx[k] <= ceff) ? 1 : 0;
            int j0 = min(max(jc - 1, 0), 6);
            float y0 = sel8(cx, j0);
            float y1 = sel8(cx, j0 + 1);
            float b = (ceff - y0) / (y1 - y0);
            float om_b = 1.0f - b;
            float v00 = sel8(d0, j0), v01 = sel8(d0, j0 + 1);
            float v10 = sel8(d1, j0), v11 = sel8(d1, j0 + 1);
            float d = om_a * om_b * v00 + om_a * b * v01
                    + a * om_b * v10 + a * b * v11;
            float tau = fmaxf(d, 1e-30f);
            float ratio = fminf(2.0f * tau / slew_den, 10.0f);
            float h = (ratio > 0.01f) ? (1.0f - expf(-ratio)) / ratio
                                      : 1.0f - 0.5f * ratio;
            ceff = fmaxf(c1f + c2f * h, 1e-30f);
        }
        float load = fminf(ceff, 1.0e-12f);

        // ---- final bilinear for delay and slew ----
        int jc = 0;
#pragma unroll
        for (int k = 0; k < 8; ++k) jc += (cx[k] <= load) ? 1 : 0;
        int j0 = min(max(jc - 1, 0), 6);
        float y0 = sel8(cx, j0);
        float y1 = sel8(cx, j0 + 1);
        float b = (load - y0) / (y1 - y0);
        float om_b = 1.0f - b;

        float v00 = sel8(d0, j0), v01 = sel8(d0, j0 + 1);
        float v10 = sel8(d1, j0), v11 = sel8(d1, j0 + 1);
        float delay = om_a * om_b * v00 + om_a * b * v01
                    + a * om_b * v10 + a * b * v11;

        const float* srow = stab + (size_t)arc * 64 + (size_t)i0 * 8;
        float s00 = srow[j0],     s01 = srow[j0 + 1];
        float s10 = srow[8 + j0], s11 = srow[8 + j0 + 1];
        float sl = om_a * om_b * s00 + om_a * b * s01
                 + a * om_b * s10 + a * b * s11;

        res_arr[col]  = arr + delay;
        res_slew[col] = sl;
    }

    out[t] = make_float4(res_arr[0], res_arr[1], res_slew[0], res_slew[1]);
}

extern "C" void kernel_launch(void* const* d_in, const int* in_sizes, int n_in,
                              void* d_out, int out_size, void* d_ws, size_t ws_size,
                              hipStream_t stream) {
    const float*  U      = (const float*)d_in[0];
    const int*    gid    = (const int*)d_in[1];
    const float2* in_arr = (const float2*)d_in[2];
    const float2* in_slw = (const float2*)d_in[3];
    const float*  c1     = (const float*)d_in[4];
    const float*  c2     = (const float*)d_in[5];
    // d_in[6] = rpi : unused by the reference computation
    const int*    arc_r  = (const int*)d_in[7];
    const int*    arc_f  = (const int*)d_in[8];
    const int*    una    = (const int*)d_in[9];
    const float*  dtab   = (const float*)d_in[10];
    const float*  stab   = (const float*)d_in[11];
    const float*  sidx   = (const float*)d_in[12];  // slew_index [A,8]
    const float*  lidx   = (const float*)d_in[13];  // load_index [A,8]

    float* out  = (float*)d_out;               // [T,4] = 2,000,000 floats
    float* wout = out + (size_t)T_N * 4;       // weights = 1,000,000 floats
    float* gsum = (float*)d_ws;                // G_N floats of scratch

    init_gsum_kernel<<<(G_N + 255) / 256, 256, 0, stream>>>(gsum);
    exp_sum_kernel<<<(U_N + 255) / 256, 256, 0, stream>>>(U, gid, wout, gsum);
    norm_w_kernel<<<(U_N + 255) / 256, 256, 0, stream>>>(gid, wout, gsum);

    timing_kernel<<<(T_N + 255) / 256, 256, 0, stream>>>(
        in_arr, in_slw, c1, c2, arc_r, arc_f, una, dtab, stab, sidx, lidx,
        (float4*)out);
}